// Round 5
// baseline (455.296 us; speedup 1.0000x reference)
//
#include <hip/hip_runtime.h>
#include <hip/hip_bf16.h>

#define SEQ    2048
#define BATCH  2
#define MTOK   4096
#define EMBED  1024
#define HEADS  16
#define HDIM   64
#define QKV3   3072
#define FFN    4096

typedef __attribute__((ext_vector_type(8))) short bf16x8;
typedef __attribute__((ext_vector_type(4))) float f32x4;

static __device__ __forceinline__ unsigned short f2bf(float f) {
  union { float f; unsigned u; } x; x.f = f;
  unsigned r = x.u + 0x7FFFu + ((x.u >> 16) & 1u);
  return (unsigned short)(r >> 16);
}
static __device__ __forceinline__ float bf2f(unsigned short u) {
  union { unsigned u; float f; } x; x.u = ((unsigned)u) << 16; return x.f;
}
static __device__ __forceinline__ unsigned pk2bf(float a, float b) {
#if __has_builtin(__builtin_amdgcn_cvt_pk_bf16_f32)
  typedef __attribute__((ext_vector_type(2))) __bf16 bf16x2_t;
  union { bf16x2_t v; unsigned u; } x;
  x.v = __builtin_amdgcn_cvt_pk_bf16_f32(a, b);
  return x.u;
#else
  return ((unsigned)f2bf(a)) | (((unsigned)f2bf(b)) << 16);
#endif
}

// async global->LDS, 16B per lane; lds dest is wave-uniform base + lane*16
static __device__ __forceinline__ void gload16(const unsigned short* g, unsigned short* l) {
  __builtin_amdgcn_global_load_lds((const __attribute__((address_space(1))) void*)g,
                                   (__attribute__((address_space(3))) void*)l, 16, 0, 0);
}

// ---------------- fused weight transpose + fp32->bf16: Wt[n][k] = W[k][n] (all 4 weights)
struct TD { const float* W; unsigned short* T; int K, N, ntx, base; };
struct TD4 { TD d[4]; };

__global__ void transpose_all(TD4 td) {
  __shared__ float t[32][33];
  int bid = blockIdx.x;
  int i = 0;
  if (bid >= td.d[1].base) i = 1;
  if (bid >= td.d[2].base) i = 2;
  if (bid >= td.d[3].base) i = 3;
  const TD& D = td.d[i];
  int local = bid - D.base;
  int n0 = (local % D.ntx) * 32, k0 = (local / D.ntx) * 32;
  int tx = threadIdx.x, ty = threadIdx.y;  // block (32,8)
#pragma unroll
  for (int j = 0; j < 32; j += 8)
    t[ty + j][tx] = D.W[(size_t)(k0 + ty + j) * D.N + n0 + tx];
  __syncthreads();
#pragma unroll
  for (int j = 0; j < 32; j += 8)
    D.T[(size_t)(n0 + ty + j) * D.K + k0 + tx] = f2bf(t[tx][ty + j]);
}

// ---------------- layernorm (one token per block), fp32 in -> bf16 out
__global__ __launch_bounds__(256) void ln_kernel(const float* __restrict__ in,
                                                 const float* __restrict__ w,
                                                 const float* __restrict__ b,
                                                 unsigned short* __restrict__ out) {
  __shared__ float sh[4];
  int row = blockIdx.x, tid = threadIdx.x;
  const float4 v = ((const float4*)(in + (size_t)row * EMBED))[tid];
  float s = v.x + v.y + v.z + v.w;
#pragma unroll
  for (int off = 32; off; off >>= 1) s += __shfl_xor(s, off);
  if ((tid & 63) == 0) sh[tid >> 6] = s;
  __syncthreads();
  float mean = (sh[0] + sh[1] + sh[2] + sh[3]) * (1.0f / EMBED);
  __syncthreads();
  float dx = v.x - mean, dy = v.y - mean, dz = v.z - mean, dw = v.w - mean;
  float q = dx * dx + dy * dy + dz * dz + dw * dw;
#pragma unroll
  for (int off = 32; off; off >>= 1) q += __shfl_xor(q, off);
  if ((tid & 63) == 0) sh[tid >> 6] = q;
  __syncthreads();
  float var = (sh[0] + sh[1] + sh[2] + sh[3]) * (1.0f / EMBED);
  float rs = rsqrtf(var + 1e-5f);
  const float4 wv = ((const float4*)w)[tid];
  const float4 bv = ((const float4*)b)[tid];
  ushort4 o;
  o.x = f2bf(dx * rs * wv.x + bv.x);
  o.y = f2bf(dy * rs * wv.y + bv.y);
  o.z = f2bf(dz * rs * wv.z + bv.z);
  o.w = f2bf(dw * rs * wv.w + bv.w);
  ((ushort4*)(out + (size_t)row * EMBED))[tid] = o;
}

// ---------------- 128x128 NT bf16 MFMA GEMM (m97 structure), BK=32, XCD-swizzled 1-D grid
template <int ACT, int RES, int OUTBF, int VSPLIT>
__global__ __launch_bounds__(256) void gemm128(const unsigned short* __restrict__ A,
                                               const unsigned short* __restrict__ Wt,
                                               const float* __restrict__ bias,
                                               const float* __restrict__ res,
                                               unsigned short* __restrict__ outB,
                                               float* __restrict__ outF,
                                               unsigned short* __restrict__ vT,
                                               int M, int N, int K, int nblk) {
  __shared__ __align__(16) unsigned short As[128 * 32];
  __shared__ __align__(16) unsigned short Bs[128 * 32];
  const int tid = threadIdx.x;
  const int wave = tid >> 6, lane = tid & 63;
  const int quad = lane >> 4, ml = lane & 15;
  const int wr = wave >> 1, wc = wave & 1;
  const int xcd = blockIdx.x & 7, idx = blockIdx.x >> 3;
  const int mPerXcd = (gridDim.x >> 3) / nblk;
  const int m0 = (xcd * mPerXcd + idx / nblk) * 128;
  const int n0 = (idx % nblk) * 128;
  const int sr = lane >> 2, sc = (lane & 3) * 8;
  const unsigned short* Ag = A + (size_t)(m0 + wave * 32 + sr) * K + sc;
  const unsigned short* Bg = Wt + (size_t)(n0 + wave * 32 + sr) * K + sc;
  unsigned short* AsW = &As[wave * 1024];
  unsigned short* BsW = &Bs[wave * 1024];
  f32x4 acc[4][4];
#pragma unroll
  for (int i = 0; i < 4; i++)
#pragma unroll
    for (int j = 0; j < 4; j++) acc[i][j] = (f32x4){0.f, 0.f, 0.f, 0.f};
  for (int k0 = 0; k0 < K; k0 += 32) {
    __syncthreads();
    gload16(Ag, AsW);
    gload16(Ag + (size_t)16 * K, AsW + 512);
    gload16(Bg, BsW);
    gload16(Bg + (size_t)16 * K, BsW + 512);
    Ag += 32; Bg += 32;
    __syncthreads();
    bf16x8 af[4], bfr[4];
#pragma unroll
    for (int mt = 0; mt < 4; mt++)
      af[mt] = *(const bf16x8*)&As[(wr * 64 + mt * 16 + ml) * 32 + quad * 8];
#pragma unroll
    for (int nt = 0; nt < 4; nt++)
      bfr[nt] = *(const bf16x8*)&Bs[(wc * 64 + nt * 16 + ml) * 32 + quad * 8];
#pragma unroll
    for (int mt = 0; mt < 4; mt++)
#pragma unroll
      for (int nt = 0; nt < 4; nt++)
        acc[mt][nt] = __builtin_amdgcn_mfma_f32_16x16x32_bf16(af[mt], bfr[nt], acc[mt][nt], 0, 0, 0);
  }
#pragma unroll
  for (int mt = 0; mt < 4; mt++)
#pragma unroll
    for (int nt = 0; nt < 4; nt++) {
      const int col0 = n0 + wc * 64 + nt * 16;
      const int row0 = m0 + wr * 64 + mt * 16;
      if (VSPLIT && col0 >= 2 * EMBED) {
        const int b = row0 >> 11, tok0 = row0 & (SEQ - 1);
        const int h = (col0 - 2 * EMBED) >> 6;
        const int dl = ((col0 - 2 * EMBED) & 63) + ml;
        float bia = bias[col0 + ml];
        ushort4 o;
        o.x = f2bf(acc[mt][nt][0] + bia);
        o.y = f2bf(acc[mt][nt][1] + bia);
        o.z = f2bf(acc[mt][nt][2] + bia);
        o.w = f2bf(acc[mt][nt][3] + bia);
        *(ushort4*)(vT + (size_t)((b * 16 + h) * 64 + dl) * SEQ + tok0 + quad * 4) = o;
      } else {
#pragma unroll
        for (int r = 0; r < 4; r++) {
          int row = row0 + quad * 4 + r;
          int col = col0 + ml;
          float v = acc[mt][nt][r] + bias[col];
          if (ACT) v = 0.5f * v * (1.0f + erff(v * 0.70710678118f));
          if (RES) v += res[(size_t)row * N + col];
          if (OUTBF)
            outB[(size_t)row * N + col] = f2bf(v);
          else
            outF[(size_t)row * N + col] = v;
        }
      }
    }
}

// ---------------- 128x64 NT GEMM, BK=64, XOR-swizzled LDS, XCD-swizzled grid
template <int RES, int OUTBF>
__global__ __launch_bounds__(256) void gemm64k(const unsigned short* __restrict__ A,
                                               const unsigned short* __restrict__ Wt,
                                               const float* __restrict__ bias,
                                               const float* __restrict__ res,
                                               unsigned short* __restrict__ outB,
                                               float* __restrict__ outF,
                                               int M, int N, int K, int nblk) {
  __shared__ __align__(16) unsigned short As[128 * 64];
  __shared__ __align__(16) unsigned short Bs[64 * 64];
  const int tid = threadIdx.x;
  const int wave = tid >> 6, lane = tid & 63;
  const int quad = lane >> 4, ml = lane & 15;
  const int wr = wave >> 1, wc = wave & 1;
  const int xcd = blockIdx.x & 7, idx = blockIdx.x >> 3;
  const int mPerXcd = (gridDim.x >> 3) / nblk;
  const int m0 = (xcd * mPerXcd + idx / nblk) * 128;
  const int n0 = (idx % nblk) * 64;
  const int srow = lane >> 3;
  const int schunk = (lane & 7) ^ (srow & 7);
  const unsigned short* Ag = A + (size_t)(m0 + wave * 32 + srow) * K + schunk * 8;
  const unsigned short* Bg = Wt + (size_t)(n0 + wave * 16 + srow) * K + schunk * 8;
  unsigned short* AsW = &As[wave * 2048];
  unsigned short* BsW = &Bs[wave * 1024];
  f32x4 acc[4][2];
#pragma unroll
  for (int i = 0; i < 4; i++) { acc[i][0] = (f32x4){0.f,0.f,0.f,0.f}; acc[i][1] = acc[i][0]; }
  for (int k0 = 0; k0 < K; k0 += 64) {
    __syncthreads();
    gload16(Ag, AsW);
    gload16(Ag + (size_t)8 * K,  AsW + 512);
    gload16(Ag + (size_t)16 * K, AsW + 1024);
    gload16(Ag + (size_t)24 * K, AsW + 1536);
    gload16(Bg, BsW);
    gload16(Bg + (size_t)8 * K,  BsW + 512);
    Ag += 64; Bg += 64;
    __syncthreads();
#pragma unroll
    for (int kh = 0; kh < 2; kh++) {
      const int ch = ((kh * 4 + quad) ^ (ml & 7)) * 8;
      bf16x8 af[4], bfr[2];
#pragma unroll
      for (int mt = 0; mt < 4; mt++)
        af[mt] = *(const bf16x8*)&As[(wr * 64 + mt * 16 + ml) * 64 + ch];
#pragma unroll
      for (int nt = 0; nt < 2; nt++)
        bfr[nt] = *(const bf16x8*)&Bs[(wc * 32 + nt * 16 + ml) * 64 + ch];
#pragma unroll
      for (int mt = 0; mt < 4; mt++)
#pragma unroll
        for (int nt = 0; nt < 2; nt++)
          acc[mt][nt] = __builtin_amdgcn_mfma_f32_16x16x32_bf16(af[mt], bfr[nt], acc[mt][nt], 0, 0, 0);
    }
  }
#pragma unroll
  for (int mt = 0; mt < 4; mt++)
#pragma unroll
    for (int nt = 0; nt < 2; nt++)
#pragma unroll
      for (int r = 0; r < 4; r++) {
        int row = m0 + wr * 64 + mt * 16 + quad * 4 + r;
        int col = n0 + wc * 32 + nt * 16 + ml;
        float v = acc[mt][nt][r] + bias[col];
        if (RES) v += res[(size_t)row * N + col];
        if (OUTBF)
          outB[(size_t)row * N + col] = f2bf(v);
        else
          outF[(size_t)row * N + col] = v;
      }
}

// ---------------- flash attention, key-split waves
// grid (SEQ/64, BATCH*HEADS); block = 4 waves; block owns 64 queries, iterates 128 keys;
// wave w handles keys [kt + w*32, +32) x all 64 queries. S^T MFMA (A=K, B=Q) ->
// lane owns 4 adjacent keys -> b64 P-writes. Partial O/lsum combined via LDS atomics.
#define PSTR 40  // P row stride (us); 80B rows -> 2-way max on frag reads
__global__ __launch_bounds__(256, 2) void attn_kernel(const unsigned short* __restrict__ qkv,
                                                      const unsigned short* __restrict__ vT,
                                                      unsigned short* __restrict__ attn) {
  __shared__ __align__(16) unsigned short Ks[128 * 64];      // [key][dim] chunk-swizzled
  __shared__ __align__(16) unsigned short Vt[64 * 128];      // [dim][key] chunk-swizzled
  __shared__ __align__(16) unsigned short Ps[4 * 64 * PSTR]; // per-wave P[q][k(32)]
  const int tid = threadIdx.x, wave = tid >> 6, lane = tid & 63;
  const int quad = lane >> 4, ml = lane & 15;
  const int bh = blockIdx.y, b = bh >> 4, h = bh & 15;
  const int q0 = blockIdx.x * 64;

  // Q fragments (all waves: queries q0+t*16+ml), prescaled by 0.125*log2(e)
  const float qscale = 0.18033688011112042f;
  bf16x8 qb[4][2];
#pragma unroll
  for (int t = 0; t < 4; t++) {
    const unsigned short* qrow = qkv + (size_t)(b * SEQ + q0 + t * 16 + ml) * QKV3 + h * HDIM;
    bf16x8 v0 = *(const bf16x8*)(qrow + quad * 8);
    bf16x8 v1 = *(const bf16x8*)(qrow + 32 + quad * 8);
#pragma unroll
    for (int j = 0; j < 8; j++) {
      v0[j] = (short)f2bf(bf2f((unsigned short)v0[j]) * qscale);
      v1[j] = (short)f2bf(bf2f((unsigned short)v1[j]) * qscale);
    }
    qb[t][0] = v0; qb[t][1] = v1;
  }
  bf16x8 ones;
#pragma unroll
  for (int j = 0; j < 8; j++) ones[j] = (short)0x3F80;

  f32x4 O[4][4], lsum[4];
#pragma unroll
  for (int t = 0; t < 4; t++) {
    lsum[t] = (f32x4){0.f, 0.f, 0.f, 0.f};
#pragma unroll
    for (int d = 0; d < 4; d++) O[t][d] = (f32x4){0.f, 0.f, 0.f, 0.f};
  }

  // K staging: wave w stages keys w*32..+31 (4 issues x 8 rows of 128B)
  const int srow = lane >> 3;                      // row within issue
  const int kchk = ((lane & 7) ^ srow) * 8;        // XOR-swizzled dim chunk
  const unsigned short* kg =
      qkv + (size_t)(b * SEQ + wave * 32 + srow) * QKV3 + EMBED + h * HDIM + kchk;
  unsigned short* KsW = &Ks[wave * 2048];
  // V staging: wave w stages dims w*16..+15 (4 issues x 4 rows of 256B)
  const int vrow = lane >> 4;
  size_t voff[4];
#pragma unroll
  for (int i = 0; i < 4; i++) {
    int dim = wave * 16 + i * 4 + vrow;
    int chk = ((lane & 15) ^ ((i * 4 + vrow) & 15)) * 8;
    voff[i] = (size_t)(bh * 64 + dim) * SEQ + chk;
  }
  unsigned short* VsW = &Vt[wave * 2048];
  unsigned short* Psw = &Ps[wave * 64 * PSTR];

  for (int kt = 0; kt < SEQ; kt += 128) {
    __syncthreads();
#pragma unroll
    for (int i = 0; i < 4; i++) gload16(kg + (size_t)(kt + i * 8) * QKV3, KsW + i * 512);
#pragma unroll
    for (int i = 0; i < 4; i++) gload16(vT + voff[i] + kt, VsW + i * 512);
    __syncthreads();
    // S^T = K Q^T : keys = rows. Per s: 16 keys x 64 queries.
#pragma unroll
    for (int s = 0; s < 2; s++) {
      const int krow = wave * 32 + s * 16 + ml;
      bf16x8 ka0 = *(const bf16x8*)&Ks[krow * 64 + ((quad ^ (ml & 7))) * 8];
      bf16x8 ka1 = *(const bf16x8*)&Ks[krow * 64 + (((4 + quad) ^ (ml & 7))) * 8];
      f32x4 S[4];
#pragma unroll
      for (int t = 0; t < 4; t++) {
        S[t] = (f32x4){0.f, 0.f, 0.f, 0.f};
        S[t] = __builtin_amdgcn_mfma_f32_16x16x32_bf16(ka0, qb[t][0], S[t], 0, 0, 0);
        S[t] = __builtin_amdgcn_mfma_f32_16x16x32_bf16(ka1, qb[t][1], S[t], 0, 0, 0);
      }
#pragma unroll
      for (int t = 0; t < 4; t++) {
        uint2 pk_;
        pk_.x = pk2bf(exp2f(S[t][0]), exp2f(S[t][1]));
        pk_.y = pk2bf(exp2f(S[t][2]), exp2f(S[t][3]));
        *(uint2*)&Psw[(t * 16 + ml) * PSTR + s * 16 + quad * 4] = pk_;
      }
    }
    // lsum + PV over this wave's 32-key chunk
    bf16x8 ap[4];
#pragma unroll
    for (int t = 0; t < 4; t++) {
      ap[t] = *(const bf16x8*)&Psw[(t * 16 + ml) * PSTR + quad * 8];
      lsum[t] = __builtin_amdgcn_mfma_f32_16x16x32_bf16(ap[t], ones, lsum[t], 0, 0, 0);
    }
#pragma unroll
    for (int d = 0; d < 4; d++) {
      bf16x8 vb = *(const bf16x8*)&Vt[(d * 16 + ml) * 128 + (((wave * 4 + quad) ^ ml) & 15) * 8];
#pragma unroll
      for (int t = 0; t < 4; t++)
        O[t][d] = __builtin_amdgcn_mfma_f32_16x16x32_bf16(ap[t], vb, O[t][d], 0, 0, 0);
    }
  }

  // cross-wave combine
  __syncthreads();
  float* Of = (float*)Ks;  // 64q x 64d fp32 = 16 KB
  float* Ls = (float*)Vt;  // 64 fp32
  if (wave == 0) {
#pragma unroll
    for (int t = 0; t < 4; t++) {
#pragma unroll
      for (int d = 0; d < 4; d++)
#pragma unroll
        for (int r = 0; r < 4; r++)
          Of[(t * 16 + quad * 4 + r) * 64 + d * 16 + ml] = O[t][d][r];
      if (ml == 0)
#pragma unroll
        for (int r = 0; r < 4; r++) Ls[t * 16 + quad * 4 + r] = lsum[t][r];
    }
  }
  __syncthreads();
  if (wave != 0) {
#pragma unroll
    for (int t = 0; t < 4; t++) {
#pragma unroll
      for (int d = 0; d < 4; d++)
#pragma unroll
        for (int r = 0; r < 4; r++)
          atomicAdd(&Of[(t * 16 + quad * 4 + r) * 64 + d * 16 + ml], O[t][d][r]);
      if (ml == 0)
#pragma unroll
        for (int r = 0; r < 4; r++) atomicAdd(&Ls[t * 16 + quad * 4 + r], lsum[t][r]);
    }
  }
  __syncthreads();
  {
    const int q = tid >> 2, ds = (tid & 3) * 16;
    const float inv = 1.0f / Ls[q];
    unsigned short o[16];
#pragma unroll
    for (int j = 0; j < 16; j++) o[j] = f2bf(Of[q * 64 + ds + j] * inv);
    unsigned short* dst = attn + (size_t)(b * SEQ + q0 + q) * EMBED + h * HDIM + ds;
    *(uint4*)dst = *(uint4*)&o[0];
    *(uint4*)(dst + 8) = *(uint4*)&o[8];
  }
}

extern "C" void kernel_launch(void* const* d_in, const int* in_sizes, int n_in,
                              void* d_out, int out_size, void* d_ws, size_t ws_size,
                              hipStream_t stream) {
  const float* x      = (const float*)d_in[0];
  const float* ln1_w  = (const float*)d_in[1];
  const float* ln1_b  = (const float*)d_in[2];
  const float* ln2_w  = (const float*)d_in[3];
  const float* ln2_b  = (const float*)d_in[4];
  const float* qkv_w  = (const float*)d_in[5];
  const float* qkv_b  = (const float*)d_in[6];
  const float* proj_w = (const float*)d_in[7];
  const float* proj_b = (const float*)d_in[8];
  const float* fc1_w  = (const float*)d_in[9];
  const float* fc1_b  = (const float*)d_in[10];
  const float* fc2_w  = (const float*)d_in[11];
  const float* fc2_b  = (const float*)d_in[12];
  float* out = (float*)d_out;
  char* wsb = (char*)d_ws;
  unsigned short* lnbuf  = (unsigned short*)(wsb + 0);
  unsigned short* qkvb   = (unsigned short*)(wsb + 8388608);
  unsigned short* attnb  = (unsigned short*)(wsb + 33554432);
  unsigned short* vTb    = (unsigned short*)(wsb + 41943040);
  unsigned short* actb   = (unsigned short*)(wsb + 33554432);
  float*          h1     = (float*)(wsb + 67108864);
  unsigned short* qkvWt  = (unsigned short*)(wsb + 83886080);
  unsigned short* projWt = (unsigned short*)(wsb + 90177536);
  unsigned short* fc1Wt  = (unsigned short*)(wsb + 92274688);
  unsigned short* fc2Wt  = (unsigned short*)(wsb + 100663296);

  TD4 td;
  td.d[0] = {qkv_w,  qkvWt,  1024, 3072,  96, 0};
  td.d[1] = {proj_w, projWt, 1024, 1024,  32, 3072};
  td.d[2] = {fc1_w,  fc1Wt,  1024, 4096, 128, 4096};
  td.d[3] = {fc2_w,  fc2Wt,  4096, 1024,  32, 8192};
  transpose_all<<<12288, dim3(32, 8), 0, stream>>>(td);

  ln_kernel<<<MTOK, 256, 0, stream>>>(x, ln1_w, ln1_b, lnbuf);
  gemm128<0, 0, 1, 1><<<768, 256, 0, stream>>>(
      lnbuf, qkvWt, qkv_b, nullptr, qkvb, nullptr, vTb, MTOK, QKV3, EMBED, 24);
  attn_kernel<<<dim3(32, 32), 256, 0, stream>>>(qkvb, vTb, attnb);
  gemm64k<1, 0><<<512, 256, 0, stream>>>(
      attnb, projWt, proj_b, x, nullptr, h1, MTOK, EMBED, EMBED, 16);
  ln_kernel<<<MTOK, 256, 0, stream>>>(h1, ln2_w, ln2_b, lnbuf);
  gemm128<1, 0, 1, 0><<<1024, 256, 0, stream>>>(
      lnbuf, fc1Wt, fc1_b, nullptr, actb, nullptr, nullptr, MTOK, FFN, EMBED, 32);
  gemm64k<1, 0><<<512, 256, 0, stream>>>(
      actb, fc2Wt, fc2_b, h1, nullptr, out, MTOK, EMBED, FFN, 16);
}

// Round 6
// 389.306 us; speedup vs baseline: 1.1695x; 1.1695x over previous
//
#include <hip/hip_runtime.h>
#include <hip/hip_bf16.h>

#define SEQ    2048
#define BATCH  2
#define MTOK   4096
#define EMBED  1024
#define HEADS  16
#define HDIM   64
#define QKV3   3072
#define FFN    4096

typedef __attribute__((ext_vector_type(8))) short bf16x8;
typedef __attribute__((ext_vector_type(4))) float f32x4;

static __device__ __forceinline__ unsigned short f2bf(float f) {
  union { float f; unsigned u; } x; x.f = f;
  unsigned r = x.u + 0x7FFFu + ((x.u >> 16) & 1u);
  return (unsigned short)(r >> 16);
}
static __device__ __forceinline__ float bf2f(unsigned short u) {
  union { unsigned u; float f; } x; x.u = ((unsigned)u) << 16; return x.f;
}
static __device__ __forceinline__ unsigned pk2bf(float a, float b) {
#if __has_builtin(__builtin_amdgcn_cvt_pk_bf16_f32)
  typedef __attribute__((ext_vector_type(2))) __bf16 bf16x2_t;
  union { bf16x2_t v; unsigned u; } x;
  x.v = __builtin_amdgcn_cvt_pk_bf16_f32(a, b);
  return x.u;
#else
  return ((unsigned)f2bf(a)) | (((unsigned)f2bf(b)) << 16);
#endif
}

// async global->LDS, 16B per lane; lds dest is wave-uniform base + lane*16
static __device__ __forceinline__ void gload16(const unsigned short* g, unsigned short* l) {
  __builtin_amdgcn_global_load_lds((const __attribute__((address_space(1))) void*)g,
                                   (__attribute__((address_space(3))) void*)l, 16, 0, 0);
}

// ---------------- fused weight transpose + fp32->bf16: Wt[n][k] = W[k][n] (all 4 weights)
struct TD { const float* W; unsigned short* T; int K, N, ntx, base; };
struct TD4 { TD d[4]; };

__global__ void transpose_all(TD4 td) {
  __shared__ float t[32][33];
  int bid = blockIdx.x;
  int i = 0;
  if (bid >= td.d[1].base) i = 1;
  if (bid >= td.d[2].base) i = 2;
  if (bid >= td.d[3].base) i = 3;
  const TD& D = td.d[i];
  int local = bid - D.base;
  int n0 = (local % D.ntx) * 32, k0 = (local / D.ntx) * 32;
  int tx = threadIdx.x, ty = threadIdx.y;  // block (32,8)
#pragma unroll
  for (int j = 0; j < 32; j += 8)
    t[ty + j][tx] = D.W[(size_t)(k0 + ty + j) * D.N + n0 + tx];
  __syncthreads();
#pragma unroll
  for (int j = 0; j < 32; j += 8)
    D.T[(size_t)(n0 + ty + j) * D.K + k0 + tx] = f2bf(t[tx][ty + j]);
}

// ---------------- layernorm (one token per block), fp32 in -> bf16 out
__global__ __launch_bounds__(256) void ln_kernel(const float* __restrict__ in,
                                                 const float* __restrict__ w,
                                                 const float* __restrict__ b,
                                                 unsigned short* __restrict__ out) {
  __shared__ float sh[4];
  int row = blockIdx.x, tid = threadIdx.x;
  const float4 v = ((const float4*)(in + (size_t)row * EMBED))[tid];
  float s = v.x + v.y + v.z + v.w;
#pragma unroll
  for (int off = 32; off; off >>= 1) s += __shfl_xor(s, off);
  if ((tid & 63) == 0) sh[tid >> 6] = s;
  __syncthreads();
  float mean = (sh[0] + sh[1] + sh[2] + sh[3]) * (1.0f / EMBED);
  __syncthreads();
  float dx = v.x - mean, dy = v.y - mean, dz = v.z - mean, dw = v.w - mean;
  float q = dx * dx + dy * dy + dz * dz + dw * dw;
#pragma unroll
  for (int off = 32; off; off >>= 1) q += __shfl_xor(q, off);
  if ((tid & 63) == 0) sh[tid >> 6] = q;
  __syncthreads();
  float var = (sh[0] + sh[1] + sh[2] + sh[3]) * (1.0f / EMBED);
  float rs = rsqrtf(var + 1e-5f);
  const float4 wv = ((const float4*)w)[tid];
  const float4 bv = ((const float4*)b)[tid];
  ushort4 o;
  o.x = f2bf(dx * rs * wv.x + bv.x);
  o.y = f2bf(dy * rs * wv.y + bv.y);
  o.z = f2bf(dz * rs * wv.z + bv.z);
  o.w = f2bf(dw * rs * wv.w + bv.w);
  ((ushort4*)(out + (size_t)row * EMBED))[tid] = o;
}

// ---------------- 128x128 NT bf16 MFMA GEMM (m97 structure), BK=32, XCD-swizzled 1-D grid
template <int ACT, int RES, int OUTBF, int VSPLIT>
__global__ __launch_bounds__(256) void gemm128(const unsigned short* __restrict__ A,
                                               const unsigned short* __restrict__ Wt,
                                               const float* __restrict__ bias,
                                               const float* __restrict__ res,
                                               unsigned short* __restrict__ outB,
                                               float* __restrict__ outF,
                                               unsigned short* __restrict__ vT,
                                               int M, int N, int K, int nblk) {
  __shared__ __align__(16) unsigned short As[128 * 32];
  __shared__ __align__(16) unsigned short Bs[128 * 32];
  const int tid = threadIdx.x;
  const int wave = tid >> 6, lane = tid & 63;
  const int quad = lane >> 4, ml = lane & 15;
  const int wr = wave >> 1, wc = wave & 1;
  const int xcd = blockIdx.x & 7, idx = blockIdx.x >> 3;
  const int mPerXcd = (gridDim.x >> 3) / nblk;
  const int m0 = (xcd * mPerXcd + idx / nblk) * 128;
  const int n0 = (idx % nblk) * 128;
  const int sr = lane >> 2, sc = (lane & 3) * 8;
  const unsigned short* Ag = A + (size_t)(m0 + wave * 32 + sr) * K + sc;
  const unsigned short* Bg = Wt + (size_t)(n0 + wave * 32 + sr) * K + sc;
  unsigned short* AsW = &As[wave * 1024];
  unsigned short* BsW = &Bs[wave * 1024];
  f32x4 acc[4][4];
#pragma unroll
  for (int i = 0; i < 4; i++)
#pragma unroll
    for (int j = 0; j < 4; j++) acc[i][j] = (f32x4){0.f, 0.f, 0.f, 0.f};
  for (int k0 = 0; k0 < K; k0 += 32) {
    __syncthreads();
    gload16(Ag, AsW);
    gload16(Ag + (size_t)16 * K, AsW + 512);
    gload16(Bg, BsW);
    gload16(Bg + (size_t)16 * K, BsW + 512);
    Ag += 32; Bg += 32;
    __syncthreads();
    bf16x8 af[4], bfr[4];
#pragma unroll
    for (int mt = 0; mt < 4; mt++)
      af[mt] = *(const bf16x8*)&As[(wr * 64 + mt * 16 + ml) * 32 + quad * 8];
#pragma unroll
    for (int nt = 0; nt < 4; nt++)
      bfr[nt] = *(const bf16x8*)&Bs[(wc * 64 + nt * 16 + ml) * 32 + quad * 8];
#pragma unroll
    for (int mt = 0; mt < 4; mt++)
#pragma unroll
      for (int nt = 0; nt < 4; nt++)
        acc[mt][nt] = __builtin_amdgcn_mfma_f32_16x16x32_bf16(af[mt], bfr[nt], acc[mt][nt], 0, 0, 0);
  }
#pragma unroll
  for (int mt = 0; mt < 4; mt++)
#pragma unroll
    for (int nt = 0; nt < 4; nt++) {
      const int col0 = n0 + wc * 64 + nt * 16;
      const int row0 = m0 + wr * 64 + mt * 16;
      if (VSPLIT && col0 >= 2 * EMBED) {
        const int b = row0 >> 11, tok0 = row0 & (SEQ - 1);
        const int h = (col0 - 2 * EMBED) >> 6;
        const int dl = ((col0 - 2 * EMBED) & 63) + ml;
        float bia = bias[col0 + ml];
        ushort4 o;
        o.x = f2bf(acc[mt][nt][0] + bia);
        o.y = f2bf(acc[mt][nt][1] + bia);
        o.z = f2bf(acc[mt][nt][2] + bia);
        o.w = f2bf(acc[mt][nt][3] + bia);
        *(ushort4*)(vT + (size_t)((b * 16 + h) * 64 + dl) * SEQ + tok0 + quad * 4) = o;
      } else {
#pragma unroll
        for (int r = 0; r < 4; r++) {
          int row = row0 + quad * 4 + r;
          int col = col0 + ml;
          float v = acc[mt][nt][r] + bias[col];
          if (ACT) v = 0.5f * v * (1.0f + erff(v * 0.70710678118f));
          if (RES) v += res[(size_t)row * N + col];
          if (OUTBF)
            outB[(size_t)row * N + col] = f2bf(v);
          else
            outF[(size_t)row * N + col] = v;
        }
      }
    }
}

// ---------------- 128x64 NT GEMM, BK=64, XOR-swizzled LDS, XCD-swizzled grid
template <int RES, int OUTBF>
__global__ __launch_bounds__(256) void gemm64k(const unsigned short* __restrict__ A,
                                               const unsigned short* __restrict__ Wt,
                                               const float* __restrict__ bias,
                                               const float* __restrict__ res,
                                               unsigned short* __restrict__ outB,
                                               float* __restrict__ outF,
                                               int M, int N, int K, int nblk) {
  __shared__ __align__(16) unsigned short As[128 * 64];
  __shared__ __align__(16) unsigned short Bs[64 * 64];
  const int tid = threadIdx.x;
  const int wave = tid >> 6, lane = tid & 63;
  const int quad = lane >> 4, ml = lane & 15;
  const int wr = wave >> 1, wc = wave & 1;
  const int xcd = blockIdx.x & 7, idx = blockIdx.x >> 3;
  const int mPerXcd = (gridDim.x >> 3) / nblk;
  const int m0 = (xcd * mPerXcd + idx / nblk) * 128;
  const int n0 = (idx % nblk) * 64;
  const int srow = lane >> 3;
  const int schunk = (lane & 7) ^ (srow & 7);
  const unsigned short* Ag = A + (size_t)(m0 + wave * 32 + srow) * K + schunk * 8;
  const unsigned short* Bg = Wt + (size_t)(n0 + wave * 16 + srow) * K + schunk * 8;
  unsigned short* AsW = &As[wave * 2048];
  unsigned short* BsW = &Bs[wave * 1024];
  f32x4 acc[4][2];
#pragma unroll
  for (int i = 0; i < 4; i++) { acc[i][0] = (f32x4){0.f,0.f,0.f,0.f}; acc[i][1] = acc[i][0]; }
  for (int k0 = 0; k0 < K; k0 += 64) {
    __syncthreads();
    gload16(Ag, AsW);
    gload16(Ag + (size_t)8 * K,  AsW + 512);
    gload16(Ag + (size_t)16 * K, AsW + 1024);
    gload16(Ag + (size_t)24 * K, AsW + 1536);
    gload16(Bg, BsW);
    gload16(Bg + (size_t)8 * K,  BsW + 512);
    Ag += 64; Bg += 64;
    __syncthreads();
#pragma unroll
    for (int kh = 0; kh < 2; kh++) {
      const int ch = ((kh * 4 + quad) ^ (ml & 7)) * 8;
      bf16x8 af[4], bfr[2];
#pragma unroll
      for (int mt = 0; mt < 4; mt++)
        af[mt] = *(const bf16x8*)&As[(wr * 64 + mt * 16 + ml) * 64 + ch];
#pragma unroll
      for (int nt = 0; nt < 2; nt++)
        bfr[nt] = *(const bf16x8*)&Bs[(wc * 32 + nt * 16 + ml) * 64 + ch];
#pragma unroll
      for (int mt = 0; mt < 4; mt++)
#pragma unroll
        for (int nt = 0; nt < 2; nt++)
          acc[mt][nt] = __builtin_amdgcn_mfma_f32_16x16x32_bf16(af[mt], bfr[nt], acc[mt][nt], 0, 0, 0);
    }
  }
#pragma unroll
  for (int mt = 0; mt < 4; mt++)
#pragma unroll
    for (int nt = 0; nt < 2; nt++)
#pragma unroll
      for (int r = 0; r < 4; r++) {
        int row = m0 + wr * 64 + mt * 16 + quad * 4 + r;
        int col = n0 + wc * 32 + nt * 16 + ml;
        float v = acc[mt][nt][r] + bias[col];
        if (RES) v += res[(size_t)row * N + col];
        if (OUTBF)
          outB[(size_t)row * N + col] = f2bf(v);
        else
          outF[(size_t)row * N + col] = v;
      }
}

// ---------------- flash attention (round-4 structure + S^T operand swap + packed P-store)
// grid (SEQ/64, BATCH*HEADS), 4 waves, 16 q-rows/wave, 64-key tiles.
// S^T = mfma(K_frag, Q_frag): lane owns 4 adjacent keys -> b64 P writes via v_cvt_pk_bf16_f32.
// Q prescaled by 0.125*log2(e). Row-sum via ones-column MFMA.
#define PS 72
__global__ __launch_bounds__(256) void attn_kernel(const unsigned short* __restrict__ qkv,
                                                   const unsigned short* __restrict__ vT,
                                                   unsigned short* __restrict__ attn) {
  __shared__ __align__(16) unsigned short Ks[64 * 64];
  __shared__ __align__(16) unsigned short Vs[64 * 64];
  __shared__ __align__(16) unsigned short Ps[4][16 * PS];
  const int tid = threadIdx.x, wave = tid >> 6, lane = tid & 63;
  const int quad = lane >> 4, ml = lane & 15;
  const int bh = blockIdx.y, b = bh >> 4, h = bh & 15;
  const int q0 = blockIdx.x * 64 + wave * 16;
  const float qscale = 0.18033688011112042f;  // 0.125 * log2(e)
  const unsigned short* qrow = qkv + (size_t)(b * SEQ + q0 + ml) * QKV3 + h * HDIM;
  bf16x8 aq0 = *(const bf16x8*)(qrow + quad * 8);
  bf16x8 aq1 = *(const bf16x8*)(qrow + 32 + quad * 8);
#pragma unroll
  for (int j = 0; j < 8; j++) {
    aq0[j] = (short)f2bf(bf2f((unsigned short)aq0[j]) * qscale);
    aq1[j] = (short)f2bf(bf2f((unsigned short)aq1[j]) * qscale);
  }
  bf16x8 ones;
#pragma unroll
  for (int j = 0; j < 8; j++) ones[j] = (short)0x3F80;  // bf16 1.0
  f32x4 O[4], lsum = {0.f, 0.f, 0.f, 0.f};
#pragma unroll
  for (int i = 0; i < 4; i++) O[i] = (f32x4){0.f, 0.f, 0.f, 0.f};
  const int skey = lane >> 3;
  const int schunk8 = (((lane & 7) ^ ((lane >> 3) & 7))) * 8;
  const int swz = (ml & 7);
  const unsigned short* kbase =
      qkv + (size_t)(b * SEQ + wave * 16 + skey) * QKV3 + EMBED + h * HDIM + schunk8;
  const unsigned short* vbase =
      vT + (size_t)(bh * 64 + wave * 16 + skey) * SEQ + schunk8;
  unsigned short* KsW = &Ks[wave * 1024];
  unsigned short* VsW = &Vs[wave * 1024];
  for (int kt = 0; kt < SEQ; kt += 64) {
    __syncthreads();
    gload16(kbase + (size_t)kt * QKV3, KsW);
    gload16(kbase + (size_t)(kt + 8) * QKV3, KsW + 512);
    gload16(vbase + kt, VsW);
    gload16(vbase + kt + (size_t)8 * SEQ, VsW + 512);
    __syncthreads();
    // S^T per key-subtile s: C col=ml=query, row=quad*4+r = key (s*16+..)
#pragma unroll
    for (int s = 0; s < 4; s++) {
      bf16x8 blo = *(const bf16x8*)&Ks[(s * 16 + ml) * 64 + (quad ^ swz) * 8];
      bf16x8 bhi = *(const bf16x8*)&Ks[(s * 16 + ml) * 64 + ((4 + quad) ^ swz) * 8];
      f32x4 St = {0.f, 0.f, 0.f, 0.f};
      St = __builtin_amdgcn_mfma_f32_16x16x32_bf16(blo, aq0, St, 0, 0, 0);
      St = __builtin_amdgcn_mfma_f32_16x16x32_bf16(bhi, aq1, St, 0, 0, 0);
      uint2 pk_;
      pk_.x = pk2bf(exp2f(St[0]), exp2f(St[1]));
      pk_.y = pk2bf(exp2f(St[2]), exp2f(St[3]));
      // P[q=ml][k = s*16 + quad*4 + 0..3]
      *(uint2*)&Ps[wave][ml * PS + s * 16 + quad * 4] = pk_;
    }
    bf16x8 ap0 = *(const bf16x8*)&Ps[wave][ml * PS + quad * 8];
    bf16x8 ap1 = *(const bf16x8*)&Ps[wave][ml * PS + 32 + quad * 8];
    lsum = __builtin_amdgcn_mfma_f32_16x16x32_bf16(ap0, ones, lsum, 0, 0, 0);
    lsum = __builtin_amdgcn_mfma_f32_16x16x32_bf16(ap1, ones, lsum, 0, 0, 0);
#pragma unroll
    for (int d = 0; d < 4; d++) {
      bf16x8 bv0 = *(const bf16x8*)&Vs[(d * 16 + ml) * 64 + (quad ^ swz) * 8];
      bf16x8 bv1 = *(const bf16x8*)&Vs[(d * 16 + ml) * 64 + ((4 + quad) ^ swz) * 8];
      O[d] = __builtin_amdgcn_mfma_f32_16x16x32_bf16(ap0, bv0, O[d], 0, 0, 0);
      O[d] = __builtin_amdgcn_mfma_f32_16x16x32_bf16(ap1, bv1, O[d], 0, 0, 0);
    }
  }
#pragma unroll
  for (int r = 0; r < 4; r++) {
    float inv = 1.0f / lsum[r];
    size_t g = (size_t)(b * SEQ + q0 + quad * 4 + r) * EMBED + h * HDIM + ml;
    attn[g + 0]  = f2bf(O[0][r] * inv);
    attn[g + 16] = f2bf(O[1][r] * inv);
    attn[g + 32] = f2bf(O[2][r] * inv);
    attn[g + 48] = f2bf(O[3][r] * inv);
  }
}

extern "C" void kernel_launch(void* const* d_in, const int* in_sizes, int n_in,
                              void* d_out, int out_size, void* d_ws, size_t ws_size,
                              hipStream_t stream) {
  const float* x      = (const float*)d_in[0];
  const float* ln1_w  = (const float*)d_in[1];
  const float* ln1_b  = (const float*)d_in[2];
  const float* ln2_w  = (const float*)d_in[3];
  const float* ln2_b  = (const float*)d_in[4];
  const float* qkv_w  = (const float*)d_in[5];
  const float* qkv_b  = (const float*)d_in[6];
  const float* proj_w = (const float*)d_in[7];
  const float* proj_b = (const float*)d_in[8];
  const float* fc1_w  = (const float*)d_in[9];
  const float* fc1_b  = (const float*)d_in[10];
  const float* fc2_w  = (const float*)d_in[11];
  const float* fc2_b  = (const float*)d_in[12];
  float* out = (float*)d_out;
  char* wsb = (char*)d_ws;
  unsigned short* lnbuf  = (unsigned short*)(wsb + 0);
  unsigned short* qkvb   = (unsigned short*)(wsb + 8388608);
  unsigned short* attnb  = (unsigned short*)(wsb + 33554432);
  unsigned short* vTb    = (unsigned short*)(wsb + 41943040);
  unsigned short* actb   = (unsigned short*)(wsb + 33554432);
  float*          h1     = (float*)(wsb + 67108864);
  unsigned short* qkvWt  = (unsigned short*)(wsb + 83886080);
  unsigned short* projWt = (unsigned short*)(wsb + 90177536);
  unsigned short* fc1Wt  = (unsigned short*)(wsb + 92274688);
  unsigned short* fc2Wt  = (unsigned short*)(wsb + 100663296);

  TD4 td;
  td.d[0] = {qkv_w,  qkvWt,  1024, 3072,  96, 0};
  td.d[1] = {proj_w, projWt, 1024, 1024,  32, 3072};
  td.d[2] = {fc1_w,  fc1Wt,  1024, 4096, 128, 4096};
  td.d[3] = {fc2_w,  fc2Wt,  4096, 1024,  32, 8192};
  transpose_all<<<12288, dim3(32, 8), 0, stream>>>(td);

  ln_kernel<<<MTOK, 256, 0, stream>>>(x, ln1_w, ln1_b, lnbuf);
  gemm128<0, 0, 1, 1><<<768, 256, 0, stream>>>(
      lnbuf, qkvWt, qkv_b, nullptr, qkvb, nullptr, vTb, MTOK, QKV3, EMBED, 24);
  attn_kernel<<<dim3(32, 32), 256, 0, stream>>>(qkvb, vTb, attnb);
  gemm64k<1, 0><<<512, 256, 0, stream>>>(
      attnb, projWt, proj_b, x, nullptr, h1, MTOK, EMBED, EMBED, 16);
  ln_kernel<<<MTOK, 256, 0, stream>>>(h1, ln2_w, ln2_b, lnbuf);
  gemm128<1, 0, 1, 0><<<1024, 256, 0, stream>>>(
      lnbuf, fc1Wt, fc1_b, nullptr, actb, nullptr, nullptr, MTOK, FFN, EMBED, 32);
  gemm64k<1, 0><<<512, 256, 0, stream>>>(
      actb, fc2Wt, fc2_b, h1, nullptr, out, MTOK, EMBED, FFN, 16);
}

// Round 7
// 370.644 us; speedup vs baseline: 1.2284x; 1.0503x over previous
//
#include <hip/hip_runtime.h>
#include <hip/hip_bf16.h>

#define SEQ    2048
#define BATCH  2
#define MTOK   4096
#define EMBED  1024
#define HEADS  16
#define HDIM   64
#define QKV3   3072
#define FFN    4096

typedef __attribute__((ext_vector_type(8))) short bf16x8;
typedef __attribute__((ext_vector_type(4))) float f32x4;

static __device__ __forceinline__ unsigned short f2bf(float f) {
  union { float f; unsigned u; } x; x.f = f;
  unsigned r = x.u + 0x7FFFu + ((x.u >> 16) & 1u);
  return (unsigned short)(r >> 16);
}
static __device__ __forceinline__ float bf2f(unsigned short u) {
  union { unsigned u; float f; } x; x.u = ((unsigned)u) << 16; return x.f;
}
static __device__ __forceinline__ unsigned pk2bf(float a, float b) {
#if __has_builtin(__builtin_amdgcn_cvt_pk_bf16_f32)
  typedef __attribute__((ext_vector_type(2))) __bf16 bf16x2_t;
  union { bf16x2_t v; unsigned u; } x;
  x.v = __builtin_amdgcn_cvt_pk_bf16_f32(a, b);
  return x.u;
#else
  return ((unsigned)f2bf(a)) | (((unsigned)f2bf(b)) << 16);
#endif
}

// async global->LDS, 16B per lane; lds dest is wave-uniform base + lane*16
static __device__ __forceinline__ void gload16(const unsigned short* g, unsigned short* l) {
  __builtin_amdgcn_global_load_lds((const __attribute__((address_space(1))) void*)g,
                                   (__attribute__((address_space(3))) void*)l, 16, 0, 0);
}

// ---------------- fused weight transpose + fp32->bf16: Wt[n][k] = W[k][n] (all 4 weights)
struct TD { const float* W; unsigned short* T; int K, N, ntx, base; };
struct TD4 { TD d[4]; };

__global__ void transpose_all(TD4 td) {
  __shared__ float t[32][33];
  int bid = blockIdx.x;
  int i = 0;
  if (bid >= td.d[1].base) i = 1;
  if (bid >= td.d[2].base) i = 2;
  if (bid >= td.d[3].base) i = 3;
  const TD& D = td.d[i];
  int local = bid - D.base;
  int n0 = (local % D.ntx) * 32, k0 = (local / D.ntx) * 32;
  int tx = threadIdx.x, ty = threadIdx.y;  // block (32,8)
#pragma unroll
  for (int j = 0; j < 32; j += 8)
    t[ty + j][tx] = D.W[(size_t)(k0 + ty + j) * D.N + n0 + tx];
  __syncthreads();
#pragma unroll
  for (int j = 0; j < 32; j += 8)
    D.T[(size_t)(n0 + ty + j) * D.K + k0 + tx] = f2bf(t[tx][ty + j]);
}

// ---------------- layernorm (one token per block), fp32 in -> bf16 out
__global__ __launch_bounds__(256) void ln_kernel(const float* __restrict__ in,
                                                 const float* __restrict__ w,
                                                 const float* __restrict__ b,
                                                 unsigned short* __restrict__ out) {
  __shared__ float sh[4];
  int row = blockIdx.x, tid = threadIdx.x;
  const float4 v = ((const float4*)(in + (size_t)row * EMBED))[tid];
  float s = v.x + v.y + v.z + v.w;
#pragma unroll
  for (int off = 32; off; off >>= 1) s += __shfl_xor(s, off);
  if ((tid & 63) == 0) sh[tid >> 6] = s;
  __syncthreads();
  float mean = (sh[0] + sh[1] + sh[2] + sh[3]) * (1.0f / EMBED);
  __syncthreads();
  float dx = v.x - mean, dy = v.y - mean, dz = v.z - mean, dw = v.w - mean;
  float q = dx * dx + dy * dy + dz * dz + dw * dw;
#pragma unroll
  for (int off = 32; off; off >>= 1) q += __shfl_xor(q, off);
  if ((tid & 63) == 0) sh[tid >> 6] = q;
  __syncthreads();
  float var = (sh[0] + sh[1] + sh[2] + sh[3]) * (1.0f / EMBED);
  float rs = rsqrtf(var + 1e-5f);
  const float4 wv = ((const float4*)w)[tid];
  const float4 bv = ((const float4*)b)[tid];
  ushort4 o;
  o.x = f2bf(dx * rs * wv.x + bv.x);
  o.y = f2bf(dy * rs * wv.y + bv.y);
  o.z = f2bf(dz * rs * wv.z + bv.z);
  o.w = f2bf(dw * rs * wv.w + bv.w);
  ((ushort4*)(out + (size_t)row * EMBED))[tid] = o;
}

// ---------------- 128x128 NT bf16 GEMM, BK=64, XOR-swizzled LDS (128B rows),
// plain n-fastest block order (XCD x statically owns n === x mod 8 -> B slice L2-resident).
template <int ACT, int OUTBF, int VSPLIT>
__global__ __launch_bounds__(256) void gemmBig(const unsigned short* __restrict__ A,
                                               const unsigned short* __restrict__ Wt,
                                               const float* __restrict__ bias,
                                               unsigned short* __restrict__ outB,
                                               float* __restrict__ outF,
                                               unsigned short* __restrict__ vT,
                                               int M, int N, int K, int nblk) {
  __shared__ __align__(16) unsigned short As[128 * 64];  // 16 KB
  __shared__ __align__(16) unsigned short Bs[128 * 64];  // 16 KB
  const int tid = threadIdx.x;
  const int wave = tid >> 6, lane = tid & 63;
  const int quad = lane >> 4, ml = lane & 15;
  const int wr = wave >> 1, wc = wave & 1;
  const int m0 = (blockIdx.x / nblk) * 128;
  const int n0 = (blockIdx.x % nblk) * 128;
  // staging: issue t covers rows wave*32 + t*8 + l/8; source chunk XOR-swizzled
  const int srow = lane >> 3;
  const int schunk = (lane & 7) ^ (srow & 7);
  const unsigned short* Ag = A + (size_t)(m0 + wave * 32 + srow) * K + schunk * 8;
  const unsigned short* Bg = Wt + (size_t)(n0 + wave * 32 + srow) * K + schunk * 8;
  unsigned short* AsW = &As[wave * 2048];
  unsigned short* BsW = &Bs[wave * 2048];
  f32x4 acc[4][4];
#pragma unroll
  for (int i = 0; i < 4; i++)
#pragma unroll
    for (int j = 0; j < 4; j++) acc[i][j] = (f32x4){0.f, 0.f, 0.f, 0.f};
  for (int k0 = 0; k0 < K; k0 += 64) {
    __syncthreads();
#pragma unroll
    for (int t = 0; t < 4; t++) {
      gload16(Ag + (size_t)(8 * t) * K, AsW + 512 * t);
      gload16(Bg + (size_t)(8 * t) * K, BsW + 512 * t);
    }
    Ag += 64; Bg += 64;
    __syncthreads();
#pragma unroll
    for (int kh = 0; kh < 2; kh++) {
      const int ch = ((kh * 4 + quad) ^ (ml & 7)) * 8;
      bf16x8 af[4], bfr[4];
#pragma unroll
      for (int mt = 0; mt < 4; mt++)
        af[mt] = *(const bf16x8*)&As[(wr * 64 + mt * 16 + ml) * 64 + ch];
#pragma unroll
      for (int nt = 0; nt < 4; nt++)
        bfr[nt] = *(const bf16x8*)&Bs[(wc * 64 + nt * 16 + ml) * 64 + ch];
#pragma unroll
      for (int mt = 0; mt < 4; mt++)
#pragma unroll
        for (int nt = 0; nt < 4; nt++)
          acc[mt][nt] = __builtin_amdgcn_mfma_f32_16x16x32_bf16(af[mt], bfr[nt], acc[mt][nt], 0, 0, 0);
    }
  }
#pragma unroll
  for (int mt = 0; mt < 4; mt++)
#pragma unroll
    for (int nt = 0; nt < 4; nt++) {
      const int col0 = n0 + wc * 64 + nt * 16;
      const int row0 = m0 + wr * 64 + mt * 16;
      if (VSPLIT && col0 >= 2 * EMBED) {
        const int b = row0 >> 11, tok0 = row0 & (SEQ - 1);
        const int h = (col0 - 2 * EMBED) >> 6;
        const int dl = ((col0 - 2 * EMBED) & 63) + ml;
        float bia = bias[col0 + ml];
        ushort4 o;
        o.x = f2bf(acc[mt][nt][0] + bia);
        o.y = f2bf(acc[mt][nt][1] + bia);
        o.z = f2bf(acc[mt][nt][2] + bia);
        o.w = f2bf(acc[mt][nt][3] + bia);
        *(ushort4*)(vT + (size_t)((b * 16 + h) * 64 + dl) * SEQ + tok0 + quad * 4) = o;
      } else {
#pragma unroll
        for (int r = 0; r < 4; r++) {
          int row = row0 + quad * 4 + r;
          int col = col0 + ml;
          float v = acc[mt][nt][r] + bias[col];
          if (ACT) v = 0.5f * v * (1.0f + erff(v * 0.70710678118f));
          if (OUTBF)
            outB[(size_t)row * N + col] = f2bf(v);
          else
            outF[(size_t)row * N + col] = v;
        }
      }
    }
}

// ---------------- 128x64 NT GEMM, BK=64, XOR-swizzled LDS, XCD m-stripe grid (for big-A GEMMs)
template <int RES, int OUTBF>
__global__ __launch_bounds__(256) void gemm64k(const unsigned short* __restrict__ A,
                                               const unsigned short* __restrict__ Wt,
                                               const float* __restrict__ bias,
                                               const float* __restrict__ res,
                                               unsigned short* __restrict__ outB,
                                               float* __restrict__ outF,
                                               int M, int N, int K, int nblk) {
  __shared__ __align__(16) unsigned short As[128 * 64];
  __shared__ __align__(16) unsigned short Bs[64 * 64];
  const int tid = threadIdx.x;
  const int wave = tid >> 6, lane = tid & 63;
  const int quad = lane >> 4, ml = lane & 15;
  const int wr = wave >> 1, wc = wave & 1;
  const int xcd = blockIdx.x & 7, idx = blockIdx.x >> 3;
  const int mPerXcd = (gridDim.x >> 3) / nblk;
  const int m0 = (xcd * mPerXcd + idx / nblk) * 128;
  const int n0 = (idx % nblk) * 64;
  const int srow = lane >> 3;
  const int schunk = (lane & 7) ^ (srow & 7);
  const unsigned short* Ag = A + (size_t)(m0 + wave * 32 + srow) * K + schunk * 8;
  const unsigned short* Bg = Wt + (size_t)(n0 + wave * 16 + srow) * K + schunk * 8;
  unsigned short* AsW = &As[wave * 2048];
  unsigned short* BsW = &Bs[wave * 1024];
  f32x4 acc[4][2];
#pragma unroll
  for (int i = 0; i < 4; i++) { acc[i][0] = (f32x4){0.f,0.f,0.f,0.f}; acc[i][1] = acc[i][0]; }
  for (int k0 = 0; k0 < K; k0 += 64) {
    __syncthreads();
    gload16(Ag, AsW);
    gload16(Ag + (size_t)8 * K,  AsW + 512);
    gload16(Ag + (size_t)16 * K, AsW + 1024);
    gload16(Ag + (size_t)24 * K, AsW + 1536);
    gload16(Bg, BsW);
    gload16(Bg + (size_t)8 * K,  BsW + 512);
    Ag += 64; Bg += 64;
    __syncthreads();
#pragma unroll
    for (int kh = 0; kh < 2; kh++) {
      const int ch = ((kh * 4 + quad) ^ (ml & 7)) * 8;
      bf16x8 af[4], bfr[2];
#pragma unroll
      for (int mt = 0; mt < 4; mt++)
        af[mt] = *(const bf16x8*)&As[(wr * 64 + mt * 16 + ml) * 64 + ch];
#pragma unroll
      for (int nt = 0; nt < 2; nt++)
        bfr[nt] = *(const bf16x8*)&Bs[(wc * 32 + nt * 16 + ml) * 64 + ch];
#pragma unroll
      for (int mt = 0; mt < 4; mt++)
#pragma unroll
        for (int nt = 0; nt < 2; nt++)
          acc[mt][nt] = __builtin_amdgcn_mfma_f32_16x16x32_bf16(af[mt], bfr[nt], acc[mt][nt], 0, 0, 0);
    }
  }
#pragma unroll
  for (int mt = 0; mt < 4; mt++)
#pragma unroll
    for (int nt = 0; nt < 2; nt++)
#pragma unroll
      for (int r = 0; r < 4; r++) {
        int row = m0 + wr * 64 + mt * 16 + quad * 4 + r;
        int col = n0 + wc * 32 + nt * 16 + ml;
        float v = acc[mt][nt][r] + bias[col];
        if (RES) v += res[(size_t)row * N + col];
        if (OUTBF)
          outB[(size_t)row * N + col] = f2bf(v);
        else
          outF[(size_t)row * N + col] = v;
      }
}

// ---------------- flash attention (S^T operand swap + packed P-store)
#define PS 72
__global__ __launch_bounds__(256) void attn_kernel(const unsigned short* __restrict__ qkv,
                                                   const unsigned short* __restrict__ vT,
                                                   unsigned short* __restrict__ attn) {
  __shared__ __align__(16) unsigned short Ks[64 * 64];
  __shared__ __align__(16) unsigned short Vs[64 * 64];
  __shared__ __align__(16) unsigned short Ps[4][16 * PS];
  const int tid = threadIdx.x, wave = tid >> 6, lane = tid & 63;
  const int quad = lane >> 4, ml = lane & 15;
  const int bh = blockIdx.y, b = bh >> 4, h = bh & 15;
  const int q0 = blockIdx.x * 64 + wave * 16;
  const float qscale = 0.18033688011112042f;  // 0.125 * log2(e)
  const unsigned short* qrow = qkv + (size_t)(b * SEQ + q0 + ml) * QKV3 + h * HDIM;
  bf16x8 aq0 = *(const bf16x8*)(qrow + quad * 8);
  bf16x8 aq1 = *(const bf16x8*)(qrow + 32 + quad * 8);
#pragma unroll
  for (int j = 0; j < 8; j++) {
    aq0[j] = (short)f2bf(bf2f((unsigned short)aq0[j]) * qscale);
    aq1[j] = (short)f2bf(bf2f((unsigned short)aq1[j]) * qscale);
  }
  bf16x8 ones;
#pragma unroll
  for (int j = 0; j < 8; j++) ones[j] = (short)0x3F80;  // bf16 1.0
  f32x4 O[4], lsum = {0.f, 0.f, 0.f, 0.f};
#pragma unroll
  for (int i = 0; i < 4; i++) O[i] = (f32x4){0.f, 0.f, 0.f, 0.f};
  const int skey = lane >> 3;
  const int schunk8 = (((lane & 7) ^ ((lane >> 3) & 7))) * 8;
  const int swz = (ml & 7);
  const unsigned short* kbase =
      qkv + (size_t)(b * SEQ + wave * 16 + skey) * QKV3 + EMBED + h * HDIM + schunk8;
  const unsigned short* vbase =
      vT + (size_t)(bh * 64 + wave * 16 + skey) * SEQ + schunk8;
  unsigned short* KsW = &Ks[wave * 1024];
  unsigned short* VsW = &Vs[wave * 1024];
  for (int kt = 0; kt < SEQ; kt += 64) {
    __syncthreads();
    gload16(kbase + (size_t)kt * QKV3, KsW);
    gload16(kbase + (size_t)(kt + 8) * QKV3, KsW + 512);
    gload16(vbase + kt, VsW);
    gload16(vbase + kt + (size_t)8 * SEQ, VsW + 512);
    __syncthreads();
#pragma unroll
    for (int s = 0; s < 4; s++) {
      bf16x8 blo = *(const bf16x8*)&Ks[(s * 16 + ml) * 64 + (quad ^ swz) * 8];
      bf16x8 bhi = *(const bf16x8*)&Ks[(s * 16 + ml) * 64 + ((4 + quad) ^ swz) * 8];
      f32x4 St = {0.f, 0.f, 0.f, 0.f};
      St = __builtin_amdgcn_mfma_f32_16x16x32_bf16(blo, aq0, St, 0, 0, 0);
      St = __builtin_amdgcn_mfma_f32_16x16x32_bf16(bhi, aq1, St, 0, 0, 0);
      uint2 pk_;
      pk_.x = pk2bf(exp2f(St[0]), exp2f(St[1]));
      pk_.y = pk2bf(exp2f(St[2]), exp2f(St[3]));
      *(uint2*)&Ps[wave][ml * PS + s * 16 + quad * 4] = pk_;
    }
    bf16x8 ap0 = *(const bf16x8*)&Ps[wave][ml * PS + quad * 8];
    bf16x8 ap1 = *(const bf16x8*)&Ps[wave][ml * PS + 32 + quad * 8];
    lsum = __builtin_amdgcn_mfma_f32_16x16x32_bf16(ap0, ones, lsum, 0, 0, 0);
    lsum = __builtin_amdgcn_mfma_f32_16x16x32_bf16(ap1, ones, lsum, 0, 0, 0);
#pragma unroll
    for (int d = 0; d < 4; d++) {
      bf16x8 bv0 = *(const bf16x8*)&Vs[(d * 16 + ml) * 64 + (quad ^ swz) * 8];
      bf16x8 bv1 = *(const bf16x8*)&Vs[(d * 16 + ml) * 64 + ((4 + quad) ^ swz) * 8];
      O[d] = __builtin_amdgcn_mfma_f32_16x16x32_bf16(ap0, bv0, O[d], 0, 0, 0);
      O[d] = __builtin_amdgcn_mfma_f32_16x16x32_bf16(ap1, bv1, O[d], 0, 0, 0);
    }
  }
#pragma unroll
  for (int r = 0; r < 4; r++) {
    float inv = 1.0f / lsum[r];
    size_t g = (size_t)(b * SEQ + q0 + quad * 4 + r) * EMBED + h * HDIM + ml;
    attn[g + 0]  = f2bf(O[0][r] * inv);
    attn[g + 16] = f2bf(O[1][r] * inv);
    attn[g + 32] = f2bf(O[2][r] * inv);
    attn[g + 48] = f2bf(O[3][r] * inv);
  }
}

extern "C" void kernel_launch(void* const* d_in, const int* in_sizes, int n_in,
                              void* d_out, int out_size, void* d_ws, size_t ws_size,
                              hipStream_t stream) {
  const float* x      = (const float*)d_in[0];
  const float* ln1_w  = (const float*)d_in[1];
  const float* ln1_b  = (const float*)d_in[2];
  const float* ln2_w  = (const float*)d_in[3];
  const float* ln2_b  = (const float*)d_in[4];
  const float* qkv_w  = (const float*)d_in[5];
  const float* qkv_b  = (const float*)d_in[6];
  const float* proj_w = (const float*)d_in[7];
  const float* proj_b = (const float*)d_in[8];
  const float* fc1_w  = (const float*)d_in[9];
  const float* fc1_b  = (const float*)d_in[10];
  const float* fc2_w  = (const float*)d_in[11];
  const float* fc2_b  = (const float*)d_in[12];
  float* out = (float*)d_out;
  char* wsb = (char*)d_ws;
  unsigned short* lnbuf  = (unsigned short*)(wsb + 0);
  unsigned short* qkvb   = (unsigned short*)(wsb + 8388608);
  unsigned short* attnb  = (unsigned short*)(wsb + 33554432);
  unsigned short* vTb    = (unsigned short*)(wsb + 41943040);
  unsigned short* actb   = (unsigned short*)(wsb + 33554432);
  float*          h1     = (float*)(wsb + 67108864);
  unsigned short* qkvWt  = (unsigned short*)(wsb + 83886080);
  unsigned short* projWt = (unsigned short*)(wsb + 90177536);
  unsigned short* fc1Wt  = (unsigned short*)(wsb + 92274688);
  unsigned short* fc2Wt  = (unsigned short*)(wsb + 100663296);

  TD4 td;
  td.d[0] = {qkv_w,  qkvWt,  1024, 3072,  96, 0};
  td.d[1] = {proj_w, projWt, 1024, 1024,  32, 3072};
  td.d[2] = {fc1_w,  fc1Wt,  1024, 4096, 128, 4096};
  td.d[3] = {fc2_w,  fc2Wt,  4096, 1024,  32, 8192};
  transpose_all<<<12288, dim3(32, 8), 0, stream>>>(td);

  ln_kernel<<<MTOK, 256, 0, stream>>>(x, ln1_w, ln1_b, lnbuf);
  gemmBig<0, 1, 1><<<768, 256, 0, stream>>>(
      lnbuf, qkvWt, qkv_b, qkvb, nullptr, vTb, MTOK, QKV3, EMBED, 24);
  attn_kernel<<<dim3(32, 32), 256, 0, stream>>>(qkvb, vTb, attnb);
  gemm64k<1, 0><<<512, 256, 0, stream>>>(
      attnb, projWt, proj_b, x, nullptr, h1, MTOK, EMBED, EMBED, 16);
  ln_kernel<<<MTOK, 256, 0, stream>>>(h1, ln2_w, ln2_b, lnbuf);
  gemmBig<1, 1, 0><<<1024, 256, 0, stream>>>(
      lnbuf, fc1Wt, fc1_b, actb, nullptr, nullptr, MTOK, FFN, EMBED, 32);
  gemm64k<1, 0><<<512, 256, 0, stream>>>(
      actb, fc2Wt, fc2_b, h1, nullptr, out, MTOK, EMBED, FFN, 16);
}

// Round 8
// 370.508 us; speedup vs baseline: 1.2288x; 1.0004x over previous
//
#include <hip/hip_runtime.h>
#include <hip/hip_bf16.h>

#define SEQ    2048
#define BATCH  2
#define MTOK   4096
#define EMBED  1024
#define HEADS  16
#define HDIM   64
#define QKV3   3072
#define FFN    4096

typedef __attribute__((ext_vector_type(8))) short bf16x8;
typedef __attribute__((ext_vector_type(4))) float f32x4;

static __device__ __forceinline__ unsigned short f2bf(float f) {
  union { float f; unsigned u; } x; x.f = f;
  unsigned r = x.u + 0x7FFFu + ((x.u >> 16) & 1u);
  return (unsigned short)(r >> 16);
}
static __device__ __forceinline__ float bf2f(unsigned short u) {
  union { unsigned u; float f; } x; x.u = ((unsigned)u) << 16; return x.f;
}
static __device__ __forceinline__ unsigned pk2bf(float a, float b) {
#if __has_builtin(__builtin_amdgcn_cvt_pk_bf16_f32)
  typedef __attribute__((ext_vector_type(2))) __bf16 bf16x2_t;
  union { bf16x2_t v; unsigned u; } x;
  x.v = __builtin_amdgcn_cvt_pk_bf16_f32(a, b);
  return x.u;
#else
  return ((unsigned)f2bf(a)) | (((unsigned)f2bf(b)) << 16);
#endif
}

// async global->LDS, 16B per lane; lds dest is wave-uniform base + lane*16
static __device__ __forceinline__ void gload16(const unsigned short* g, unsigned short* l) {
  __builtin_amdgcn_global_load_lds((const __attribute__((address_space(1))) void*)g,
                                   (__attribute__((address_space(3))) void*)l, 16, 0, 0);
}

// ---------------- fused weight transpose + fp32->bf16: Wt[n][k] = W[k][n] (all 4 weights)
struct TD { const float* W; unsigned short* T; int K, N, ntx, base; };
struct TD4 { TD d[4]; };

__global__ void transpose_all(TD4 td) {
  __shared__ float t[32][33];
  int bid = blockIdx.x;
  int i = 0;
  if (bid >= td.d[1].base) i = 1;
  if (bid >= td.d[2].base) i = 2;
  if (bid >= td.d[3].base) i = 3;
  const TD& D = td.d[i];
  int local = bid - D.base;
  int n0 = (local % D.ntx) * 32, k0 = (local / D.ntx) * 32;
  int tx = threadIdx.x, ty = threadIdx.y;  // block (32,8)
#pragma unroll
  for (int j = 0; j < 32; j += 8)
    t[ty + j][tx] = D.W[(size_t)(k0 + ty + j) * D.N + n0 + tx];
  __syncthreads();
#pragma unroll
  for (int j = 0; j < 32; j += 8)
    D.T[(size_t)(n0 + ty + j) * D.K + k0 + tx] = f2bf(t[tx][ty + j]);
}

// ---------------- layernorm (one token per block), fp32 in -> bf16 out
__global__ __launch_bounds__(256) void ln_kernel(const float* __restrict__ in,
                                                 const float* __restrict__ w,
                                                 const float* __restrict__ b,
                                                 unsigned short* __restrict__ out) {
  __shared__ float sh[4];
  int row = blockIdx.x, tid = threadIdx.x;
  const float4 v = ((const float4*)(in + (size_t)row * EMBED))[tid];
  float s = v.x + v.y + v.z + v.w;
#pragma unroll
  for (int off = 32; off; off >>= 1) s += __shfl_xor(s, off);
  if ((tid & 63) == 0) sh[tid >> 6] = s;
  __syncthreads();
  float mean = (sh[0] + sh[1] + sh[2] + sh[3]) * (1.0f / EMBED);
  __syncthreads();
  float dx = v.x - mean, dy = v.y - mean, dz = v.z - mean, dw = v.w - mean;
  float q = dx * dx + dy * dy + dz * dz + dw * dw;
#pragma unroll
  for (int off = 32; off; off >>= 1) q += __shfl_xor(q, off);
  if ((tid & 63) == 0) sh[tid >> 6] = q;
  __syncthreads();
  float var = (sh[0] + sh[1] + sh[2] + sh[3]) * (1.0f / EMBED);
  float rs = rsqrtf(var + 1e-5f);
  const float4 wv = ((const float4*)w)[tid];
  const float4 bv = ((const float4*)b)[tid];
  ushort4 o;
  o.x = f2bf(dx * rs * wv.x + bv.x);
  o.y = f2bf(dy * rs * wv.y + bv.y);
  o.z = f2bf(dz * rs * wv.z + bv.z);
  o.w = f2bf(dw * rs * wv.w + bv.w);
  ((ushort4*)(out + (size_t)row * EMBED))[tid] = o;
}

// ---------------- 128x128 NT bf16 GEMM, BK=64, XOR-swizzled LDS (128B rows),
// plain n-fastest block order (XCD x statically owns n === x mod 8 -> B slice L2-resident).
template <int ACT, int OUTBF, int VSPLIT>
__global__ __launch_bounds__(256) void gemmBig(const unsigned short* __restrict__ A,
                                               const unsigned short* __restrict__ Wt,
                                               const float* __restrict__ bias,
                                               unsigned short* __restrict__ outB,
                                               float* __restrict__ outF,
                                               unsigned short* __restrict__ vT,
                                               int M, int N, int K, int nblk) {
  __shared__ __align__(16) unsigned short As[128 * 64];  // 16 KB
  __shared__ __align__(16) unsigned short Bs[128 * 64];  // 16 KB
  const int tid = threadIdx.x;
  const int wave = tid >> 6, lane = tid & 63;
  const int quad = lane >> 4, ml = lane & 15;
  const int wr = wave >> 1, wc = wave & 1;
  const int m0 = (blockIdx.x / nblk) * 128;
  const int n0 = (blockIdx.x % nblk) * 128;
  const int srow = lane >> 3;
  const int schunk = (lane & 7) ^ (srow & 7);
  const unsigned short* Ag = A + (size_t)(m0 + wave * 32 + srow) * K + schunk * 8;
  const unsigned short* Bg = Wt + (size_t)(n0 + wave * 32 + srow) * K + schunk * 8;
  unsigned short* AsW = &As[wave * 2048];
  unsigned short* BsW = &Bs[wave * 2048];
  f32x4 acc[4][4];
#pragma unroll
  for (int i = 0; i < 4; i++)
#pragma unroll
    for (int j = 0; j < 4; j++) acc[i][j] = (f32x4){0.f, 0.f, 0.f, 0.f};
  for (int k0 = 0; k0 < K; k0 += 64) {
    __syncthreads();
#pragma unroll
    for (int t = 0; t < 4; t++) {
      gload16(Ag + (size_t)(8 * t) * K, AsW + 512 * t);
      gload16(Bg + (size_t)(8 * t) * K, BsW + 512 * t);
    }
    Ag += 64; Bg += 64;
    __syncthreads();
#pragma unroll
    for (int kh = 0; kh < 2; kh++) {
      const int ch = ((kh * 4 + quad) ^ (ml & 7)) * 8;
      bf16x8 af[4], bfr[4];
#pragma unroll
      for (int mt = 0; mt < 4; mt++)
        af[mt] = *(const bf16x8*)&As[(wr * 64 + mt * 16 + ml) * 64 + ch];
#pragma unroll
      for (int nt = 0; nt < 4; nt++)
        bfr[nt] = *(const bf16x8*)&Bs[(wc * 64 + nt * 16 + ml) * 64 + ch];
#pragma unroll
      for (int mt = 0; mt < 4; mt++)
#pragma unroll
        for (int nt = 0; nt < 4; nt++)
          acc[mt][nt] = __builtin_amdgcn_mfma_f32_16x16x32_bf16(af[mt], bfr[nt], acc[mt][nt], 0, 0, 0);
    }
  }
#pragma unroll
  for (int mt = 0; mt < 4; mt++)
#pragma unroll
    for (int nt = 0; nt < 4; nt++) {
      const int col0 = n0 + wc * 64 + nt * 16;
      const int row0 = m0 + wr * 64 + mt * 16;
      if (VSPLIT && col0 >= 2 * EMBED) {
        const int b = row0 >> 11, tok0 = row0 & (SEQ - 1);
        const int h = (col0 - 2 * EMBED) >> 6;
        const int dl = ((col0 - 2 * EMBED) & 63) + ml;
        float bia = bias[col0 + ml];
        ushort4 o;
        o.x = f2bf(acc[mt][nt][0] + bia);
        o.y = f2bf(acc[mt][nt][1] + bia);
        o.z = f2bf(acc[mt][nt][2] + bia);
        o.w = f2bf(acc[mt][nt][3] + bia);
        *(ushort4*)(vT + (size_t)((b * 16 + h) * 64 + dl) * SEQ + tok0 + quad * 4) = o;
      } else {
#pragma unroll
        for (int r = 0; r < 4; r++) {
          int row = row0 + quad * 4 + r;
          int col = col0 + ml;
          float v = acc[mt][nt][r] + bias[col];
          if (ACT) v = 0.5f * v * (1.0f + erff(v * 0.70710678118f));
          if (OUTBF)
            outB[(size_t)row * N + col] = f2bf(v);
          else
            outF[(size_t)row * N + col] = v;
        }
      }
    }
}

// ---------------- 128x64 NT GEMM, BK=64, XOR-swizzled LDS, XCD m-stripe grid (for big-A GEMMs)
template <int RES, int OUTBF>
__global__ __launch_bounds__(256) void gemm64k(const unsigned short* __restrict__ A,
                                               const unsigned short* __restrict__ Wt,
                                               const float* __restrict__ bias,
                                               const float* __restrict__ res,
                                               unsigned short* __restrict__ outB,
                                               float* __restrict__ outF,
                                               int M, int N, int K, int nblk) {
  __shared__ __align__(16) unsigned short As[128 * 64];
  __shared__ __align__(16) unsigned short Bs[64 * 64];
  const int tid = threadIdx.x;
  const int wave = tid >> 6, lane = tid & 63;
  const int quad = lane >> 4, ml = lane & 15;
  const int wr = wave >> 1, wc = wave & 1;
  const int xcd = blockIdx.x & 7, idx = blockIdx.x >> 3;
  const int mPerXcd = (gridDim.x >> 3) / nblk;
  const int m0 = (xcd * mPerXcd + idx / nblk) * 128;
  const int n0 = (idx % nblk) * 64;
  const int srow = lane >> 3;
  const int schunk = (lane & 7) ^ (srow & 7);
  const unsigned short* Ag = A + (size_t)(m0 + wave * 32 + srow) * K + schunk * 8;
  const unsigned short* Bg = Wt + (size_t)(n0 + wave * 16 + srow) * K + schunk * 8;
  unsigned short* AsW = &As[wave * 2048];
  unsigned short* BsW = &Bs[wave * 1024];
  f32x4 acc[4][2];
#pragma unroll
  for (int i = 0; i < 4; i++) { acc[i][0] = (f32x4){0.f,0.f,0.f,0.f}; acc[i][1] = acc[i][0]; }
  for (int k0 = 0; k0 < K; k0 += 64) {
    __syncthreads();
    gload16(Ag, AsW);
    gload16(Ag + (size_t)8 * K,  AsW + 512);
    gload16(Ag + (size_t)16 * K, AsW + 1024);
    gload16(Ag + (size_t)24 * K, AsW + 1536);
    gload16(Bg, BsW);
    gload16(Bg + (size_t)8 * K,  BsW + 512);
    Ag += 64; Bg += 64;
    __syncthreads();
#pragma unroll
    for (int kh = 0; kh < 2; kh++) {
      const int ch = ((kh * 4 + quad) ^ (ml & 7)) * 8;
      bf16x8 af[4], bfr[2];
#pragma unroll
      for (int mt = 0; mt < 4; mt++)
        af[mt] = *(const bf16x8*)&As[(wr * 64 + mt * 16 + ml) * 64 + ch];
#pragma unroll
      for (int nt = 0; nt < 2; nt++)
        bfr[nt] = *(const bf16x8*)&Bs[(wc * 32 + nt * 16 + ml) * 64 + ch];
#pragma unroll
      for (int mt = 0; mt < 4; mt++)
#pragma unroll
        for (int nt = 0; nt < 2; nt++)
          acc[mt][nt] = __builtin_amdgcn_mfma_f32_16x16x32_bf16(af[mt], bfr[nt], acc[mt][nt], 0, 0, 0);
    }
  }
#pragma unroll
  for (int mt = 0; mt < 4; mt++)
#pragma unroll
    for (int nt = 0; nt < 2; nt++)
#pragma unroll
      for (int r = 0; r < 4; r++) {
        int row = m0 + wr * 64 + mt * 16 + quad * 4 + r;
        int col = n0 + wc * 32 + nt * 16 + ml;
        float v = acc[mt][nt][r] + bias[col];
        if (RES) v += res[(size_t)row * N + col];
        if (OUTBF)
          outB[(size_t)row * N + col] = f2bf(v);
        else
          outF[(size_t)row * N + col] = v;
      }
}

// ---------------- flash attention (S^T operand swap + packed P-store)
// grid (x = bh FAST, y = q-tile): all q-tiles of one bh share bid%8 -> same XCD ->
// K/V/Q of that bh stay L2-resident (per-XCD working set ~3 MB < 4 MB L2).
#define PS 72
__global__ __launch_bounds__(256) void attn_kernel(const unsigned short* __restrict__ qkv,
                                                   const unsigned short* __restrict__ vT,
                                                   unsigned short* __restrict__ attn) {
  __shared__ __align__(16) unsigned short Ks[64 * 64];
  __shared__ __align__(16) unsigned short Vs[64 * 64];
  __shared__ __align__(16) unsigned short Ps[4][16 * PS];
  const int tid = threadIdx.x, wave = tid >> 6, lane = tid & 63;
  const int quad = lane >> 4, ml = lane & 15;
  const int bh = blockIdx.x, b = bh >> 4, h = bh & 15;   // bh = fast grid axis
  const int q0 = blockIdx.y * 64 + wave * 16;
  const float qscale = 0.18033688011112042f;  // 0.125 * log2(e)
  const unsigned short* qrow = qkv + (size_t)(b * SEQ + q0 + ml) * QKV3 + h * HDIM;
  bf16x8 aq0 = *(const bf16x8*)(qrow + quad * 8);
  bf16x8 aq1 = *(const bf16x8*)(qrow + 32 + quad * 8);
#pragma unroll
  for (int j = 0; j < 8; j++) {
    aq0[j] = (short)f2bf(bf2f((unsigned short)aq0[j]) * qscale);
    aq1[j] = (short)f2bf(bf2f((unsigned short)aq1[j]) * qscale);
  }
  bf16x8 ones;
#pragma unroll
  for (int j = 0; j < 8; j++) ones[j] = (short)0x3F80;  // bf16 1.0
  f32x4 O[4], lsum = {0.f, 0.f, 0.f, 0.f};
#pragma unroll
  for (int i = 0; i < 4; i++) O[i] = (f32x4){0.f, 0.f, 0.f, 0.f};
  const int skey = lane >> 3;
  const int schunk8 = (((lane & 7) ^ ((lane >> 3) & 7))) * 8;
  const int swz = (ml & 7);
  const unsigned short* kbase =
      qkv + (size_t)(b * SEQ + wave * 16 + skey) * QKV3 + EMBED + h * HDIM + schunk8;
  const unsigned short* vbase =
      vT + (size_t)(bh * 64 + wave * 16 + skey) * SEQ + schunk8;
  unsigned short* KsW = &Ks[wave * 1024];
  unsigned short* VsW = &Vs[wave * 1024];
  for (int kt = 0; kt < SEQ; kt += 64) {
    __syncthreads();
    gload16(kbase + (size_t)kt * QKV3, KsW);
    gload16(kbase + (size_t)(kt + 8) * QKV3, KsW + 512);
    gload16(vbase + kt, VsW);
    gload16(vbase + kt + (size_t)8 * SEQ, VsW + 512);
    __syncthreads();
#pragma unroll
    for (int s = 0; s < 4; s++) {
      bf16x8 blo = *(const bf16x8*)&Ks[(s * 16 + ml) * 64 + (quad ^ swz) * 8];
      bf16x8 bhi = *(const bf16x8*)&Ks[(s * 16 + ml) * 64 + ((4 + quad) ^ swz) * 8];
      f32x4 St = {0.f, 0.f, 0.f, 0.f};
      St = __builtin_amdgcn_mfma_f32_16x16x32_bf16(blo, aq0, St, 0, 0, 0);
      St = __builtin_amdgcn_mfma_f32_16x16x32_bf16(bhi, aq1, St, 0, 0, 0);
      uint2 pk_;
      pk_.x = pk2bf(exp2f(St[0]), exp2f(St[1]));
      pk_.y = pk2bf(exp2f(St[2]), exp2f(St[3]));
      *(uint2*)&Ps[wave][ml * PS + s * 16 + quad * 4] = pk_;
    }
    bf16x8 ap0 = *(const bf16x8*)&Ps[wave][ml * PS + quad * 8];
    bf16x8 ap1 = *(const bf16x8*)&Ps[wave][ml * PS + 32 + quad * 8];
    lsum = __builtin_amdgcn_mfma_f32_16x16x32_bf16(ap0, ones, lsum, 0, 0, 0);
    lsum = __builtin_amdgcn_mfma_f32_16x16x32_bf16(ap1, ones, lsum, 0, 0, 0);
#pragma unroll
    for (int d = 0; d < 4; d++) {
      bf16x8 bv0 = *(const bf16x8*)&Vs[(d * 16 + ml) * 64 + (quad ^ swz) * 8];
      bf16x8 bv1 = *(const bf16x8*)&Vs[(d * 16 + ml) * 64 + ((4 + quad) ^ swz) * 8];
      O[d] = __builtin_amdgcn_mfma_f32_16x16x32_bf16(ap0, bv0, O[d], 0, 0, 0);
      O[d] = __builtin_amdgcn_mfma_f32_16x16x32_bf16(ap1, bv1, O[d], 0, 0, 0);
    }
  }
#pragma unroll
  for (int r = 0; r < 4; r++) {
    float inv = 1.0f / lsum[r];
    size_t g = (size_t)(b * SEQ + q0 + quad * 4 + r) * EMBED + h * HDIM + ml;
    attn[g + 0]  = f2bf(O[0][r] * inv);
    attn[g + 16] = f2bf(O[1][r] * inv);
    attn[g + 32] = f2bf(O[2][r] * inv);
    attn[g + 48] = f2bf(O[3][r] * inv);
  }
}

extern "C" void kernel_launch(void* const* d_in, const int* in_sizes, int n_in,
                              void* d_out, int out_size, void* d_ws, size_t ws_size,
                              hipStream_t stream) {
  const float* x      = (const float*)d_in[0];
  const float* ln1_w  = (const float*)d_in[1];
  const float* ln1_b  = (const float*)d_in[2];
  const float* ln2_w  = (const float*)d_in[3];
  const float* ln2_b  = (const float*)d_in[4];
  const float* qkv_w  = (const float*)d_in[5];
  const float* qkv_b  = (const float*)d_in[6];
  const float* proj_w = (const float*)d_in[7];
  const float* proj_b = (const float*)d_in[8];
  const float* fc1_w  = (const float*)d_in[9];
  const float* fc1_b  = (const float*)d_in[10];
  const float* fc2_w  = (const float*)d_in[11];
  const float* fc2_b  = (const float*)d_in[12];
  float* out = (float*)d_out;
  char* wsb = (char*)d_ws;
  unsigned short* lnbuf  = (unsigned short*)(wsb + 0);
  unsigned short* qkvb   = (unsigned short*)(wsb + 8388608);
  unsigned short* attnb  = (unsigned short*)(wsb + 33554432);
  unsigned short* vTb    = (unsigned short*)(wsb + 41943040);
  unsigned short* actb   = (unsigned short*)(wsb + 33554432);
  float*          h1     = (float*)(wsb + 67108864);
  unsigned short* qkvWt  = (unsigned short*)(wsb + 83886080);
  unsigned short* projWt = (unsigned short*)(wsb + 90177536);
  unsigned short* fc1Wt  = (unsigned short*)(wsb + 92274688);
  unsigned short* fc2Wt  = (unsigned short*)(wsb + 100663296);

  TD4 td;
  td.d[0] = {qkv_w,  qkvWt,  1024, 3072,  96, 0};
  td.d[1] = {proj_w, projWt, 1024, 1024,  32, 3072};
  td.d[2] = {fc1_w,  fc1Wt,  1024, 4096, 128, 4096};
  td.d[3] = {fc2_w,  fc2Wt,  4096, 1024,  32, 8192};
  transpose_all<<<12288, dim3(32, 8), 0, stream>>>(td);

  ln_kernel<<<MTOK, 256, 0, stream>>>(x, ln1_w, ln1_b, lnbuf);
  gemmBig<0, 1, 1><<<768, 256, 0, stream>>>(
      lnbuf, qkvWt, qkv_b, qkvb, nullptr, vTb, MTOK, QKV3, EMBED, 24);
  attn_kernel<<<dim3(32, 32), 256, 0, stream>>>(qkvb, vTb, attnb);
  gemm64k<1, 0><<<512, 256, 0, stream>>>(
      attnb, projWt, proj_b, x, nullptr, h1, MTOK, EMBED, EMBED, 16);
  ln_kernel<<<MTOK, 256, 0, stream>>>(h1, ln2_w, ln2_b, lnbuf);
  gemmBig<1, 1, 0><<<1024, 256, 0, stream>>>(
      lnbuf, fc1Wt, fc1_b, actb, nullptr, nullptr, MTOK, FFN, EMBED, 32);
  gemm64k<1, 0><<<512, 256, 0, stream>>>(
      actb, fc2Wt, fc2_b, h1, nullptr, out, MTOK, EMBED, FFN, 16);
}